// Round 5
// baseline (262.456 us; speedup 1.0000x reference)
//
#include <hip/hip_runtime.h>

typedef _Float16 half8 __attribute__((ext_vector_type(8)));
typedef _Float16 half4v __attribute__((ext_vector_type(4)));
typedef float f32x4 __attribute__((ext_vector_type(4)));

#define OFF_PRED 26214400      // 32*128*128*50
#define OFF_XU   56934400      // OFF_PRED + 32*64*300*50

// LDS tile: 64 rows x 320 fp16, row stride 640 B, XOR-swizzled: bits 4-6 of the
// byte offset are XORed with row&7.  swz(row, byte) = row*640 + (byte ^ ((row&7)<<4))

// ---- K0: build stacked weight matrix M[640][320] fp16: 0..255=C, 256..555=A, rest 0
__global__ void build_M(const float* __restrict__ A, const float* __restrict__ C,
                        _Float16* __restrict__ M) {
    int idx = blockIdx.x * 256 + threadIdx.x;
    if (idx >= 640 * 320) return;
    int m = idx / 320, k = idx % 320;
    float v = 0.f;
    if (k < 300) {
        if (m < 256) v = C[m * 300 + k];
        else if (m < 556) v = A[(m - 256) * 300 + k];
    }
    M[idx] = (_Float16)v;
}

// ---- K1: per-(b,p) GEMM  Y[640][64] = M · [x0 | X_bp], fused scatter epilogue.
//      16 waves: wave w -> m-group g=w>>1 (rows 80g..80g+80), n-half h=w&1 (cols 32h..32h+32).
//      acc = 5 m-tiles x 2 n-tiles = 40 VGPRs -> fits 128-reg budget (4 waves/SIMD) w/ slack.
__global__ __launch_bounds__(1024, 1) void gemm_main(
    const float* __restrict__ X, const float* __restrict__ x0,
    const _Float16* __restrict__ M, float* __restrict__ out)
{
    __shared__ _Float16 lds[64 * 320];   // 40960 B
    char* ldsb = (char*)lds;
    const int bp = blockIdx.x;
    const int b = bp >> 6, p = bp & 63;
    const int tid = threadIdx.x;
    const float* Xbp = X + bp * 15000;

    const int wave = tid >> 6, lane = tid & 63;
    const int lr = lane & 15, lg = lane >> 4;
    const int g = wave >> 1, h = wave & 1;

    // ---- stage [x0 | X_bp]^T into LDS (fp16, swizzled) ----
    // zero pad k in [300,320) for all 64 rows
    if (tid < 320) {
        int row = tid / 5, c = tid % 5;
        *(half4v*)(ldsb + row * 640 + ((600 + c * 8) ^ ((row & 7) << 4))) =
            (half4v){(_Float16)0.f, (_Float16)0.f, (_Float16)0.f, (_Float16)0.f};
    }
    // x0 -> row 0 (row 0 swizzle = identity)
    if (tid < 75) {
        const float* s = x0 + bp * 300 + tid * 4;
        half4v h4 = { (_Float16)s[0], (_Float16)s[1], (_Float16)s[2], (_Float16)s[3] };
        *(half4v*)(ldsb + tid * 8) = h4;
    }
    // X (k-major [300][50]) -> LDS rows n=t+1 (transposed), 8B swizzled writes
    for (int i = tid; i < 3750; i += 1024) {
        int t = i % 50, jq = i / 50;
        const float* s = Xbp + (jq * 4) * 50 + t;
        half4v h4 = { (_Float16)s[0], (_Float16)s[50], (_Float16)s[100], (_Float16)s[150] };
        int row = t + 1;
        *(half4v*)(ldsb + row * 640 + ((jq * 8) ^ ((row & 7) << 4))) = h4;
    }
    __syncthreads();

    f32x4 acc[5][2];
    #pragma unroll
    for (int j = 0; j < 5; j++)
        #pragma unroll
        for (int nt = 0; nt < 2; nt++)
            acc[j][nt] = (f32x4){0.f, 0.f, 0.f, 0.f};

    // B-frag (M, linear): lane holds col m = g*80 + j*16 + lr, k = ks*32 + lg*8 + e
    const _Float16* Mw = M + (g * 80 + lr) * 320 + lg * 8;
    // A-frag read: row = h*32 + nt*16 + lr, byte = row*640 + ((ks*64 + lg*16) ^ ((row&7)<<4))
    #define LDSA(nt, ks) (*(const half8*)(ldsb + (h * 32 + (nt) * 16 + lr) * 640 + \
                         (((ks) * 64 + lg * 16) ^ ((lr & 7) << 4))))

    #pragma unroll
    for (int ks = 0; ks < 10; ks++) {
        half8 bf0 = *(const half8*)(Mw + 0 * 5120 + ks * 32);
        half8 bf1 = *(const half8*)(Mw + 1 * 5120 + ks * 32);
        half8 bf2 = *(const half8*)(Mw + 2 * 5120 + ks * 32);
        half8 bf3 = *(const half8*)(Mw + 3 * 5120 + ks * 32);
        half8 bf4 = *(const half8*)(Mw + 4 * 5120 + ks * 32);
        #pragma unroll
        for (int nt = 0; nt < 2; nt++) {
            half8 a = LDSA(nt, ks);
            acc[0][nt] = __builtin_amdgcn_mfma_f32_16x16x32_f16(a, bf0, acc[0][nt], 0, 0, 0);
            acc[1][nt] = __builtin_amdgcn_mfma_f32_16x16x32_f16(a, bf1, acc[1][nt], 0, 0, 0);
            acc[2][nt] = __builtin_amdgcn_mfma_f32_16x16x32_f16(a, bf2, acc[2][nt], 0, 0, 0);
            acc[3][nt] = __builtin_amdgcn_mfma_f32_16x16x32_f16(a, bf3, acc[3][nt], 0, 0, 0);
            acc[4][nt] = __builtin_amdgcn_mfma_f32_16x16x32_f16(a, bf4, acc[4][nt], 0, 0, 0);
        }
    }

    // epilogue: D elem: col m = g*80 + j*16 + lr, ext-col n = h*32 + nt*16 + lg*4 + q
    const int gr = p >> 3, gc = p & 7;
    #pragma unroll
    for (int j = 0; j < 5; j++) {
        int colm = g * 80 + j * 16 + lr;
        if (colm < 256) {
            // recon row d = colm -> vid[b][gr*16 + d/16][gc*16 + d%16][t], t = n-1
            int base = b * 819200 + ((gr * 16 + (colm >> 4)) * 128 + gc * 16 + (colm & 15)) * 50;
            #pragma unroll
            for (int nt = 0; nt < 2; nt++) {
                int t0 = h * 32 + nt * 16 + lg * 4;   // = n start
                if (t0 == 0) {
                    out[base + 0] = acc[j][0][1];
                    out[base + 1] = acc[j][0][2];
                    out[base + 2] = acc[j][0][3];
                } else if (t0 <= 46) {
                    f32x4 v = acc[j][nt];
                    __builtin_memcpy(&out[base + t0 - 1], &v, 16);
                } else if (t0 == 48) {
                    out[base + 47] = acc[j][nt][0];
                    out[base + 48] = acc[j][nt][1];
                    out[base + 49] = acc[j][nt][2];
                }
            }
        } else if (colm < 556) {
            // X_pred row i = colm-256, t = n
            int base = OFF_PRED + (bp * 300 + (colm - 256)) * 50;
            #pragma unroll
            for (int nt = 0; nt < 2; nt++) {
                int t0 = h * 32 + nt * 16 + lg * 4;
                if (t0 <= 46) {
                    f32x4 v = acc[j][nt];
                    __builtin_memcpy(&out[base + t0], &v, 16);
                } else if (t0 == 48) {
                    out[base + 48] = acc[j][nt][0];
                    out[base + 49] = acc[j][nt][1];
                }
            }
        }
    }
}

// ---- K2: X_U[b,i,t] = 0.5*(1+exp(-(B·U)[b,i,t])) * sum_p |X[b,p,i,t]|
__global__ void xu_kernel(const float* __restrict__ X, const float* __restrict__ U,
                          const float* __restrict__ B, float* __restrict__ out) {
    int id = blockIdx.x * 256 + threadIdx.x;
    if (id >= 480000) return;
    int t = id % 50;
    int i = (id / 50) % 300;
    int b = id / 15000;
    const float* xp = X + b * 960000 + i * 50 + t;
    float s = 0.f;
    #pragma unroll 8
    for (int pp = 0; pp < 64; pp++) s += fabsf(xp[pp * 15000]);
    float bu = 0.f;
    const float* up = U + b * 2000 + t;
    const float* Bp = B + i * 40;
    #pragma unroll 8
    for (int q = 0; q < 40; q++) bu += Bp[q] * up[q * 50];
    out[OFF_XU + id] = 0.5f * (1.f + expf(-bu)) * s;
}

extern "C" void kernel_launch(void* const* d_in, const int* in_sizes, int n_in,
                              void* d_out, int out_size, void* d_ws, size_t ws_size,
                              hipStream_t stream) {
    const float* X  = (const float*)d_in[0];
    const float* U  = (const float*)d_in[1];
    const float* x0 = (const float*)d_in[2];
    const float* A  = (const float*)d_in[3];
    const float* B  = (const float*)d_in[4];
    const float* C  = (const float*)d_in[5];
    float* out = (float*)d_out;
    _Float16* M = (_Float16*)d_ws;      // 640*320*2 = 409,600 B

    build_M<<<800, 256, 0, stream>>>(A, C, M);
    gemm_main<<<2048, 1024, 0, stream>>>(X, x0, M, out);
    xu_kernel<<<1875, 256, 0, stream>>>(X, U, B, out);
}

// Round 6
// 147.072 us; speedup vs baseline: 1.7845x; 1.7845x over previous
//
#include <hip/hip_runtime.h>

typedef _Float16 half8 __attribute__((ext_vector_type(8)));
typedef _Float16 half4v __attribute__((ext_vector_type(4)));
typedef float f32x4 __attribute__((ext_vector_type(4)));

#define OFF_PRED 26214400      // 32*128*128*50
#define OFF_XU   56934400      // OFF_PRED + 32*64*300*50

// LDS tile: 64 rows x 320 fp16, row stride 640 B, XOR-swizzled: bits 4-6 of the
// byte offset are XORed with row&7.  swz(row, byte) = row*640 + (byte ^ ((row&7)<<4))

// ---- K0: build M in MFMA-fragment order.
// Logical M[640][320]: rows 0..255 = C, 256..555 = A, rest 0; cols k<300 real, else 0.
// Fragment layout: dst elem = ((mt*10 + ks)*64 + lane)*8 + e, where
//   m = mt*16 + (lane&15), k = ks*32 + (lane>>4)*8 + e.
// A wave's B-frag load for (mt,ks) is then a single contiguous 1KB burst.
__global__ void build_M(const float* __restrict__ A, const float* __restrict__ C,
                        _Float16* __restrict__ M) {
    int idx = blockIdx.x * 256 + threadIdx.x;   // dst element index
    if (idx >= 640 * 320) return;
    int e    = idx & 7;
    int lane = (idx >> 3) & 63;
    int fs   = idx >> 9;                        // mt*10 + ks
    int mt = fs / 10, ks = fs % 10;
    int m = mt * 16 + (lane & 15);
    int k = ks * 32 + (lane >> 4) * 8 + e;
    float v = 0.f;
    if (k < 300) {
        if (m < 256) v = C[m * 300 + k];
        else if (m < 556) v = A[(m - 256) * 300 + k];
    }
    M[idx] = (_Float16)v;
}

// ---- K1: per-(b,p) GEMM  Y[640][64] = M · [x0 | X_bp], fused scatter epilogue.
//      16 waves: wave w -> m-group g=w>>1 (rows 80g..80g+80), n-half h=w&1 (cols 32h..32h+32).
//      acc = 5 m-tiles x 2 n-tiles = 40 VGPRs.
__global__ __launch_bounds__(1024, 1) void gemm_main(
    const float* __restrict__ X, const float* __restrict__ x0,
    const _Float16* __restrict__ M, float* __restrict__ out)
{
    __shared__ _Float16 lds[64 * 320];   // 40960 B
    char* ldsb = (char*)lds;
    const int bp = blockIdx.x;
    const int b = bp >> 6, p = bp & 63;
    const int tid = threadIdx.x;
    const float* Xbp = X + bp * 15000;

    const int wave = tid >> 6, lane = tid & 63;
    const int lr = lane & 15, lg = lane >> 4;
    const int g = wave >> 1, h = wave & 1;

    // ---- stage [x0 | X_bp]^T into LDS (fp16, swizzled) ----
    // zero pad k in [300,320) for all 64 rows
    if (tid < 320) {
        int row = tid / 5, c = tid % 5;
        *(half4v*)(ldsb + row * 640 + ((600 + c * 8) ^ ((row & 7) << 4))) =
            (half4v){(_Float16)0.f, (_Float16)0.f, (_Float16)0.f, (_Float16)0.f};
    }
    // x0 -> row 0 (row 0 swizzle = identity)
    if (tid < 75) {
        const float* s = x0 + bp * 300 + tid * 4;
        half4v h4 = { (_Float16)s[0], (_Float16)s[1], (_Float16)s[2], (_Float16)s[3] };
        *(half4v*)(ldsb + tid * 8) = h4;
    }
    // X (k-major [300][50]) -> LDS rows n=t+1 (transposed), 8B swizzled writes
    for (int i = tid; i < 3750; i += 1024) {
        int t = i % 50, jq = i / 50;
        const float* s = Xbp + (jq * 4) * 50 + t;
        half4v h4 = { (_Float16)s[0], (_Float16)s[50], (_Float16)s[100], (_Float16)s[150] };
        int row = t + 1;
        *(half4v*)(ldsb + row * 640 + ((jq * 8) ^ ((row & 7) << 4))) = h4;
    }
    __syncthreads();

    f32x4 acc[5][2];
    #pragma unroll
    for (int j = 0; j < 5; j++)
        #pragma unroll
        for (int nt = 0; nt < 2; nt++)
            acc[j][nt] = (f32x4){0.f, 0.f, 0.f, 0.f};

    // B-frag (fragment-ordered M): frag (mt = g*5+j, ks) at byte offset ((mt*10+ks)*64 + lane)*16
    const _Float16* Mw = M + (g * 5 * 10) * 512 + lane * 8;
    // A-frag read: row = h*32 + nt*16 + lr, byte = row*640 + ((ks*64 + lg*16) ^ ((row&7)<<4))
    #define LDSA(nt, ks) (*(const half8*)(ldsb + (h * 32 + (nt) * 16 + lr) * 640 + \
                         (((ks) * 64 + lg * 16) ^ ((lr & 7) << 4))))

    #pragma unroll
    for (int ks = 0; ks < 10; ks++) {
        half8 bf0 = *(const half8*)(Mw + (0 * 10 + ks) * 512);
        half8 bf1 = *(const half8*)(Mw + (1 * 10 + ks) * 512);
        half8 bf2 = *(const half8*)(Mw + (2 * 10 + ks) * 512);
        half8 bf3 = *(const half8*)(Mw + (3 * 10 + ks) * 512);
        half8 bf4 = *(const half8*)(Mw + (4 * 10 + ks) * 512);
        #pragma unroll
        for (int nt = 0; nt < 2; nt++) {
            half8 a = LDSA(nt, ks);
            acc[0][nt] = __builtin_amdgcn_mfma_f32_16x16x32_f16(a, bf0, acc[0][nt], 0, 0, 0);
            acc[1][nt] = __builtin_amdgcn_mfma_f32_16x16x32_f16(a, bf1, acc[1][nt], 0, 0, 0);
            acc[2][nt] = __builtin_amdgcn_mfma_f32_16x16x32_f16(a, bf2, acc[2][nt], 0, 0, 0);
            acc[3][nt] = __builtin_amdgcn_mfma_f32_16x16x32_f16(a, bf3, acc[3][nt], 0, 0, 0);
            acc[4][nt] = __builtin_amdgcn_mfma_f32_16x16x32_f16(a, bf4, acc[4][nt], 0, 0, 0);
        }
    }

    // epilogue: D elem: col m = g*80 + j*16 + lr, ext-col n = h*32 + nt*16 + lg*4 + q
    const int gr = p >> 3, gc = p & 7;
    #pragma unroll
    for (int j = 0; j < 5; j++) {
        int colm = g * 80 + j * 16 + lr;
        if (colm < 256) {
            // recon row d = colm -> vid[b][gr*16 + d/16][gc*16 + d%16][t], t = n-1
            int base = b * 819200 + ((gr * 16 + (colm >> 4)) * 128 + gc * 16 + (colm & 15)) * 50;
            #pragma unroll
            for (int nt = 0; nt < 2; nt++) {
                int t0 = h * 32 + nt * 16 + lg * 4;   // = n start
                if (t0 == 0) {
                    out[base + 0] = acc[j][0][1];
                    out[base + 1] = acc[j][0][2];
                    out[base + 2] = acc[j][0][3];
                } else if (t0 <= 46) {
                    f32x4 v = acc[j][nt];
                    __builtin_memcpy(&out[base + t0 - 1], &v, 16);
                } else if (t0 == 48) {
                    out[base + 47] = acc[j][nt][0];
                    out[base + 48] = acc[j][nt][1];
                    out[base + 49] = acc[j][nt][2];
                }
            }
        } else if (colm < 556) {
            // X_pred row i = colm-256, t = n
            int base = OFF_PRED + (bp * 300 + (colm - 256)) * 50;
            #pragma unroll
            for (int nt = 0; nt < 2; nt++) {
                int t0 = h * 32 + nt * 16 + lg * 4;
                if (t0 <= 46) {
                    f32x4 v = acc[j][nt];
                    __builtin_memcpy(&out[base + t0], &v, 16);
                } else if (t0 == 48) {
                    out[base + 48] = acc[j][nt][0];
                    out[base + 49] = acc[j][nt][1];
                }
            }
        }
    }
}

// ---- K2: X_U[b,i,t] = 0.5*(1+exp(-(B·U)[b,i,t])) * sum_p |X[b,p,i,t]|
__global__ void xu_kernel(const float* __restrict__ X, const float* __restrict__ U,
                          const float* __restrict__ B, float* __restrict__ out) {
    int id = blockIdx.x * 256 + threadIdx.x;
    if (id >= 480000) return;
    int t = id % 50;
    int i = (id / 50) % 300;
    int b = id / 15000;
    const float* xp = X + b * 960000 + i * 50 + t;
    float s = 0.f;
    #pragma unroll 8
    for (int pp = 0; pp < 64; pp++) s += fabsf(xp[pp * 15000]);
    float bu = 0.f;
    const float* up = U + b * 2000 + t;
    const float* Bp = B + i * 40;
    #pragma unroll 8
    for (int q = 0; q < 40; q++) bu += Bp[q] * up[q * 50];
    out[OFF_XU + id] = 0.5f * (1.f + expf(-bu)) * s;
}

extern "C" void kernel_launch(void* const* d_in, const int* in_sizes, int n_in,
                              void* d_out, int out_size, void* d_ws, size_t ws_size,
                              hipStream_t stream) {
    const float* X  = (const float*)d_in[0];
    const float* U  = (const float*)d_in[1];
    const float* x0 = (const float*)d_in[2];
    const float* A  = (const float*)d_in[3];
    const float* B  = (const float*)d_in[4];
    const float* C  = (const float*)d_in[5];
    float* out = (float*)d_out;
    _Float16* M = (_Float16*)d_ws;      // 640*320*2 = 409,600 B (fragment-ordered)

    build_M<<<800, 256, 0, stream>>>(A, C, M);
    gemm_main<<<2048, 1024, 0, stream>>>(X, x0, M, out);
    xu_kernel<<<1875, 256, 0, stream>>>(X, U, B, out);
}